// Round 2
// baseline (9301.178 us; speedup 1.0000x reference)
//
#include <hip/hip_runtime.h>
#include <cstdint>
#include <cstddef>

// ---------------------------------------------------------------------------
// LSTMModel: B=128, T=256(->255 diffs), F=6, H=512, L=4, S=32, D=3
// R2: persistent kernel, weights resident in LDS, flag-based layer-wavefront
// pipeline, mfma_f32_32x32x16_bf16 with LDS z-exchange for the cell update.
// ---------------------------------------------------------------------------

typedef __bf16 bf16x8  __attribute__((ext_vector_type(8)));
typedef float  f32x4   __attribute__((ext_vector_type(4)));
typedef float  f32x16  __attribute__((ext_vector_type(16)));

#define HLS 65536ull            // elems per (slot,layer): 128*512
#define HSS (4ull*HLS)          // elems per slot (4 layers)

// ws byte offsets
#define OFF_H    0ull
#define SZ_H     (256ull*HSS*2ull)                  // 134217728
#define OFF_D    (OFF_H + SZ_H)
#define SZ_D     524288ull
#define OFF_C    (OFF_D + SZ_D)
#define SZ_C     (4ull*128ull*512ull*4ull)          // 1048576
#define OFF_BIAS (OFF_C + SZ_C)
#define SZ_BIAS  32768ull
#define OFF_FLAG (OFF_BIAS + SZ_BIAS)
#define SZ_FLAG  (256ull*4ull*2ull*4ull)            // int flags[256][4][2]
#define OFF_BP   (OFF_FLAG + SZ_FLAG)
// bp element offsets (ushort elems)
#define BPE_L0   (64ull*48ull*64ull*8ull)           // 1572864 (l0, NK16=48 padded)
#define BPE_STR  (64ull*64ull*64ull*8ull)           // 2097152 (l>=1, NK16=64)

#define LDS_ZPAD 72                                  // zsm row stride (dwords)
#define LDS_ZBYTES (64*LDS_ZPAD*4)                   // 18432
#define LDS_WBYTES (2*64*64*8*2)                     // 131072 (max, l>=1)
#define LDS_TOTAL  (LDS_ZBYTES + LDS_WBYTES)         // 149504

__device__ __forceinline__ unsigned short f2bf(float f) {
    unsigned int u = __builtin_bit_cast(unsigned int, f);
    unsigned int lsb = (u >> 16) & 1u;
    u += 0x7fffu + lsb;
    return (unsigned short)(u >> 16);
}
__device__ __forceinline__ float bf2f(unsigned short s) {
    unsigned int u = ((unsigned int)s) << 16;
    return __builtin_bit_cast(float, u);
}
__device__ __forceinline__ float fsig(float x)  { return 1.0f / (1.0f + __expf(-x)); }
__device__ __forceinline__ float ftanh(float x) { float e = __expf(2.0f * x); return 1.0f - 2.0f / (e + 1.0f); }

// ---------------------------------------------------------------------------
// Prep: permute bias columns. dest col c: gate=(c>>4)&3, j=(c>>6)*16+(c&15)
// ---------------------------------------------------------------------------
__global__ void prep_bias(const float* __restrict__ b, float* __restrict__ bias_ws) {
    int idx = blockIdx.x * 256 + threadIdx.x;
    if (idx >= 4 * 2048) return;
    int l = idx >> 11, c = idx & 2047;
    int j = ((c >> 6) << 4) + (c & 15);
    int gate = (c >> 4) & 3;
    bias_ws[idx] = b[l * 2048 + gate * 512 + j];
}

// ---------------------------------------------------------------------------
// Prep: weights in mfma_32x32x16 B-fragment layout, bf16.
// bp[((ct*NK16 + ks)*64 + lane)*8 + i] = B[k][c]
//   k = ks*16 + (lane>>5)*8 + i,  c = ct*32 + (lane&31)  (permuted col)
// permutation: j = (c>>6)*16 + (c&15), gate = (c>>4)&3, src col = gate*512+j
// rows: l0: k<8 -> W0 (6 real, 2 zero), 8<=k<520 -> U0[k-8], else 0 (pad)
//       l>=1: k<512 -> Wk[l-1][k], else U[l][k-512]
// ---------------------------------------------------------------------------
__global__ void prep_bp32(int layer, int NK16,
                          const float* __restrict__ W0, const float* __restrict__ Wk,
                          const float* __restrict__ U, unsigned short* __restrict__ bp) {
    int idx = blockIdx.x * 256 + threadIdx.x;
    int total = 64 * NK16 * 64;
    if (idx >= total) return;
    int lane = idx & 63;
    int rest = idx >> 6;
    int ks = rest % NK16;
    int ct = rest / NK16;
    int c = ct * 32 + (lane & 31);
    int j = ((c >> 6) << 4) + (c & 15);
    int gate = (c >> 4) & 3;
    int sc = gate * 512 + j;
    int kbase = ks * 16 + ((lane >> 5) << 3);
    unsigned short outv[8];
#pragma unroll
    for (int i = 0; i < 8; i++) {
        int k = kbase + i;
        float v = 0.0f;
        if (layer == 0) {
            if (k < 8) { if (k < 6) v = W0[(size_t)k * 2048 + sc]; }
            else if (k < 520) v = U[(size_t)(k - 8) * 2048 + sc];
        } else {
            if (k < 512) v = Wk[((size_t)(layer - 1) * 512 + k) * 2048 + sc];
            else         v = U[((size_t)layer * 512 + (k - 512)) * 2048 + sc];
        }
        outv[i] = f2bf(v);
    }
    *(uint4*)(bp + (size_t)idx * 8) = *(const uint4*)outv;
}

// ---------------------------------------------------------------------------
// Diff input: d[t][item][0..7] bf16 (6 real features, padded)
// ---------------------------------------------------------------------------
__global__ void diffk(const float* __restrict__ x, const float* __restrict__ bound,
                      unsigned short* __restrict__ dbuf) {
    int idx = blockIdx.x * 256 + threadIdx.x;
    if (idx >= 255 * 128) return;
    int item = idx & 127, t = idx >> 7;
    const float* xr = x + ((size_t)item * 256 + t) * 6;
    unsigned short row[8];
#pragma unroll
    for (int f = 0; f < 6; f++) row[f] = f2bf((xr[6 + f] - xr[f]) / bound[f]);
    row[6] = 0; row[7] = 0;
    *(uint4*)(dbuf + (size_t)idx * 8) = *(const uint4*)row;
}

// ---------------------------------------------------------------------------
// Persistent LSTM: block = (layer l, colgroup cg 0..31, m-group mg 0..1).
// Per step t: z[64 items, 64 permuted cols] = A[64,K] @ W_lds[K,64], then
// z->LDS exchange, cell update, h store (agent-scope), flag release.
// A = [h_{l-1,t} | h_{l,t-1}]  (d | h_{0,t-1} for layer 0).
// ---------------------------------------------------------------------------
__global__ __launch_bounds__(256, 1) void lstm_persist(
    const unsigned short* __restrict__ dbuf,
    unsigned short* __restrict__ hbuf,
    const unsigned short* __restrict__ bp_all,
    const float* __restrict__ bias,
    float* __restrict__ c_ws,
    int* __restrict__ flags)
{
    extern __shared__ char smem[];
    float* zsm = (float*)smem;
    unsigned short* wsm = (unsigned short*)(smem + LDS_ZBYTES);

    const int blk   = blockIdx.x;
    const int layer = blk >> 6;
    const int cg    = (blk >> 1) & 31;
    const int mg    = blk & 1;
    const int tid   = threadIdx.x;
    const int w     = tid >> 6;
    const int lane  = tid & 63;
    const int NK16  = (layer == 0) ? 48 : 64;
    const int NCH   = NK16 >> 4;            // chunks of 16 k-steps: 3 or 4

    // ---- stage this block's weight tile into LDS (once) ------------------
    {
        const unsigned short* src = bp_all
            + (layer == 0 ? 0ull : (BPE_L0 + (size_t)(layer - 1) * BPE_STR))
            + (size_t)(cg * 2) * NK16 * 64 * 8;
        int nv = 2 * NK16 * 64;             // uint4 count (6144 or 8192)
        for (int e = tid; e < nv; e += 256)
            ((uint4*)wsm)[e] = ((const uint4*)src)[e];
    }
    __syncthreads();

    // ---- per-wave constants ----------------------------------------------
    const int mt    = w >> 1;               // m-half 0..1
    const int ntl   = w & 1;                // n-tile 0..1
    const int khalf = lane >> 5;            // k sub-group
    const int arow  = mg * 64 + mt * 32 + (lane & 31);
    // cell-phase constants
    const int citem = tid & 63;
    const int gitem = mg * 64 + citem;
    const int jj0   = (tid >> 6) * 4;
    const int jglob = cg * 16 + jj0;
    const f32x4 bI = *(const f32x4*)(bias + layer * 2048 + cg * 64 + 0  + jj0);
    const f32x4 bF = *(const f32x4*)(bias + layer * 2048 + cg * 64 + 16 + jj0);
    const f32x4 bG = *(const f32x4*)(bias + layer * 2048 + cg * 64 + 32 + jj0);
    const f32x4 bO = *(const f32x4*)(bias + layer * 2048 + cg * 64 + 48 + jj0);

    for (int t = 0; t < 255; t++) {
        // ---- wait for producers (acquire: invalidates stale L1/L2) ------
        if (tid == 0) {
            if (layer > 0) {
                int* f = &flags[(t * 4 + (layer - 1)) * 2 + mg];
                while (__hip_atomic_load(f, __ATOMIC_ACQUIRE, __HIP_MEMORY_SCOPE_AGENT) < 32)
                    __builtin_amdgcn_s_sleep(1);
            }
            if (t > 0) {
                int* f = &flags[((t - 1) * 4 + layer) * 2 + mg];
                while (__hip_atomic_load(f, __ATOMIC_ACQUIRE, __HIP_MEMORY_SCOPE_AGENT) < 32)
                    __builtin_amdgcn_s_sleep(1);
            }
        }
        __syncthreads();

        // ---- A base pointers ---------------------------------------------
        const unsigned short* pO = hbuf + (size_t)t * HSS + (size_t)layer * HLS
                                   + (size_t)arow * 512 + khalf * 8;
        const unsigned short* pP = nullptr;
        const unsigned short* pD = nullptr;
        if (layer > 0)
            pP = hbuf + (size_t)(t + 1) * HSS + (size_t)(layer - 1) * HLS
                 + (size_t)arow * 512 + khalf * 8;
        else
            pD = dbuf + ((size_t)t * 128 + arow) * 8;

        auto ld_a = [&](int kc) -> uint4 {
            if (layer == 0) {
                if (kc == 0 && khalf == 0) return *(const uint4*)pD;
                return *(const uint4*)(pO + kc * 16 - 8);
            }
            return (kc < 32) ? *(const uint4*)(pP + kc * 16)
                             : *(const uint4*)(pO + (kc - 32) * 16);
        };

        f32x16 acc = {0.f,0.f,0.f,0.f,0.f,0.f,0.f,0.f,0.f,0.f,0.f,0.f,0.f,0.f,0.f,0.f};
        uint4 bufA[16], bufB[16];

        auto issue = [&](uint4 (&buf)[16], int c0) {
#pragma unroll
            for (int i = 0; i < 16; i++) buf[i] = ld_a(c0 * 16 + i);
        };
        auto consume = [&](uint4 (&buf)[16], int c0) {
#pragma unroll
            for (int i = 0; i < 16; i++) {
                const bf16x8 bv = *(const bf16x8*)(wsm +
                    ((size_t)(ntl * NK16 + c0 * 16 + i) * 64 + lane) * 8);
                acc = __builtin_amdgcn_mfma_f32_32x32x16_bf16(
                    __builtin_bit_cast(bf16x8, buf[i]), bv, acc, 0, 0, 0);
            }
        };

        // ---- pipelined k-loop: 16-step chunks, ping-pong prefetch --------
        issue(bufA, 0);
        for (int c = 0; c < NCH; c += 2) {
            if (c + 1 < NCH) issue(bufB, c + 1);
            consume(bufA, c);
            if (c + 1 < NCH) {
                if (c + 2 < NCH) issue(bufA, c + 2);
                consume(bufB, c + 1);
            }
        }

        // ---- z -> LDS exchange (MFMA C layout -> [row][col]) -------------
        {
            const int col   = ntl * 32 + (lane & 31);
            const int rbase = mt * 32 + 4 * khalf;
#pragma unroll
            for (int r = 0; r < 16; r++) {
                int row = rbase + (r & 3) + 8 * (r >> 2);
                zsm[row * LDS_ZPAD + col] = acc[r];
            }
        }
        __syncthreads();

        // ---- cell update: thread -> (item, 4 consecutive j) --------------
        {
            const float* zr = zsm + citem * LDS_ZPAD;
            f32x4 zi = *(const f32x4*)(zr + 0  + jj0);
            f32x4 zf = *(const f32x4*)(zr + 16 + jj0);
            f32x4 zg = *(const f32x4*)(zr + 32 + jj0);
            f32x4 zo = *(const f32x4*)(zr + 48 + jj0);
            size_t cidx = ((size_t)layer * 128 + gitem) * 512 + jglob;
            f32x4 cold;
            if (t > 0) cold = *(const f32x4*)(c_ws + cidx);
            else       cold = (f32x4){0.f, 0.f, 0.f, 0.f};
            f32x4 cnew;
            unsigned short hq[4];
#pragma unroll
            for (int q = 0; q < 4; q++) {
                float i_ = fsig(zi[q] + bI[q]);
                float f_ = fsig(zf[q] + bF[q]);
                float g_ = ftanh(zg[q] + bG[q]);
                float o_ = fsig(zo[q] + bO[q]);
                float cn = f_ * cold[q] + i_ * g_;
                cnew[q] = cn;
                hq[q] = f2bf(o_ * ftanh(cn));
            }
            *(f32x4*)(c_ws + cidx) = cnew;
            // agent-scope store: visible device-wide without relying on wbl2
            unsigned long long hpack;
            __builtin_memcpy(&hpack, hq, 8);
            unsigned long long* hp = (unsigned long long*)(hbuf
                + (size_t)(t + 1) * HSS + (size_t)layer * HLS
                + (size_t)gitem * 512 + jglob);
            __hip_atomic_store(hp, hpack, __ATOMIC_RELAXED, __HIP_MEMORY_SCOPE_AGENT);
        }
        __syncthreads();   // drains vmcnt: all h stores complete
        if (tid == 0)
            __hip_atomic_fetch_add(&flags[(t * 4 + layer) * 2 + mg], 1,
                                   __ATOMIC_RELEASE, __HIP_MEMORY_SCOPE_AGENT);
    }
}

// ---------------------------------------------------------------------------
// Head: out[b,s,d] = h3[223+s][b] . Wd[:,d] + bd[d];  pred = out*bound+centre
// ---------------------------------------------------------------------------
__global__ void headk(const unsigned short* __restrict__ hbuf,
                      const float* __restrict__ Wd, const float* __restrict__ bd,
                      const float* __restrict__ bound, const float* __restrict__ centre,
                      float* __restrict__ out) {
    int idx = blockIdx.x * 256 + threadIdx.x;
    if (idx >= 12288) return;
    int dd = idx % 3;
    int rest = idx / 3;
    int sdx = rest & 31;
    int b = rest >> 5;
    int t = 223 + sdx;
    const unsigned short* hr = hbuf + ((size_t)(t + 1) * 4 + 3) * HLS + (size_t)b * 512;
    float acc = 0.0f;
    for (int jj = 0; jj < 512; jj++) acc += bf2f(hr[jj]) * Wd[jj * 3 + dd];
    float o = acc + bd[dd];
    out[idx] = o;
    out[12288 + idx] = o * bound[dd] + centre[dd];
}

// ---------------------------------------------------------------------------
extern "C" void kernel_launch(void* const* d_in, const int* in_sizes, int n_in,
                              void* d_out, int out_size, void* d_ws, size_t ws_size,
                              hipStream_t stream) {
    const float* x      = (const float*)d_in[0];
    const float* centre = (const float*)d_in[1];
    const float* bound  = (const float*)d_in[2];
    const float* W0     = (const float*)d_in[3];
    const float* Wk     = (const float*)d_in[4];
    const float* U      = (const float*)d_in[5];
    const float* b      = (const float*)d_in[6];
    const float* Wd     = (const float*)d_in[7];
    const float* bd     = (const float*)d_in[8];

    char* ws = (char*)d_ws;
    unsigned short* hbuf    = (unsigned short*)(ws + OFF_H);
    unsigned short* dbuf    = (unsigned short*)(ws + OFF_D);
    float*          c_ws    = (float*)(ws + OFF_C);
    float*          bias_ws = (float*)(ws + OFF_BIAS);
    int*            flags   = (int*)(ws + OFF_FLAG);
    unsigned short* bp      = (unsigned short*)(ws + OFF_BP);

    hipMemsetAsync(hbuf, 0, HSS * 2, stream);          // h slot 0 = h_{-1} = 0
    hipMemsetAsync(flags, 0, SZ_FLAG, stream);

    prep_bias<<<32, 256, 0, stream>>>(b, bias_ws);
    prep_bp32<<<768, 256, 0, stream>>>(0, 48, W0, Wk, U, bp);
    for (int l = 1; l < 4; l++)
        prep_bp32<<<1024, 256, 0, stream>>>(l, 64, W0, Wk, U,
                                            bp + BPE_L0 + (size_t)(l - 1) * BPE_STR);
    diffk<<<128, 256, 0, stream>>>(x, bound, dbuf);

    hipFuncSetAttribute((const void*)lstm_persist,
                        hipFuncAttributeMaxDynamicSharedMemorySize, LDS_TOTAL);
    lstm_persist<<<256, 256, LDS_TOTAL, stream>>>(dbuf, hbuf, bp, bias_ws, c_ws, flags);

    headk<<<48, 256, 0, stream>>>(hbuf, Wd, bd, bound, centre, (float*)d_out);
}

// Round 3
// 8675.192 us; speedup vs baseline: 1.0722x; 1.0722x over previous
//
#include <hip/hip_runtime.h>
#include <cstdint>
#include <cstddef>

// ---------------------------------------------------------------------------
// LSTMModel: B=128, T=256(->255 diffs), F=6, H=512, L=4, S=32, D=3
// R3: persistent kernel (weights LDS-resident), layer-wavefront flags with
// RELAXED polling + single ACQUIRE per step, c-state in registers.
// ---------------------------------------------------------------------------

typedef __bf16 bf16x8  __attribute__((ext_vector_type(8)));
typedef float  f32x4   __attribute__((ext_vector_type(4)));
typedef float  f32x16  __attribute__((ext_vector_type(16)));

#define HLS 65536ull            // elems per (slot,layer): 128*512
#define HSS (4ull*HLS)          // elems per slot (4 layers)

// ws byte offsets
#define OFF_H    0ull
#define SZ_H     (256ull*HSS*2ull)                  // 134217728
#define OFF_D    (OFF_H + SZ_H)
#define SZ_D     524288ull
#define OFF_BIAS (OFF_D + SZ_D)
#define SZ_BIAS  32768ull
#define OFF_FLAG (OFF_BIAS + SZ_BIAS)
#define SZ_FLAG  (256ull*4ull*2ull*4ull)            // int flags[256][4][2]
#define OFF_BP   (OFF_FLAG + SZ_FLAG)
// bp element offsets (ushort elems)
#define BPE_L0   (64ull*48ull*64ull*8ull)           // 1572864 (l0, NK16=48 padded)
#define BPE_STR  (64ull*64ull*64ull*8ull)           // 2097152 (l>=1, NK16=64)

#define LDS_ZPAD 72                                  // zsm row stride (dwords)
#define LDS_ZBYTES (64*LDS_ZPAD*4)                   // 18432
#define LDS_WBYTES (2*64*64*8*2)                     // 131072 (max, l>=1)
#define LDS_TOTAL  (LDS_ZBYTES + LDS_WBYTES)         // 149504

__device__ __forceinline__ unsigned short f2bf(float f) {
    unsigned int u = __builtin_bit_cast(unsigned int, f);
    unsigned int lsb = (u >> 16) & 1u;
    u += 0x7fffu + lsb;
    return (unsigned short)(u >> 16);
}
__device__ __forceinline__ float bf2f(unsigned short s) {
    unsigned int u = ((unsigned int)s) << 16;
    return __builtin_bit_cast(float, u);
}
__device__ __forceinline__ float fsig(float x)  { return 1.0f / (1.0f + __expf(-x)); }
__device__ __forceinline__ float ftanh(float x) { float e = __expf(2.0f * x); return 1.0f - 2.0f / (e + 1.0f); }

// ---------------------------------------------------------------------------
// Prep: permute bias columns. dest col c: gate=(c>>4)&3, j=(c>>6)*16+(c&15)
// ---------------------------------------------------------------------------
__global__ void prep_bias(const float* __restrict__ b, float* __restrict__ bias_ws) {
    int idx = blockIdx.x * 256 + threadIdx.x;
    if (idx >= 4 * 2048) return;
    int l = idx >> 11, c = idx & 2047;
    int j = ((c >> 6) << 4) + (c & 15);
    int gate = (c >> 4) & 3;
    bias_ws[idx] = b[l * 2048 + gate * 512 + j];
}

// ---------------------------------------------------------------------------
// Prep: weights in mfma_32x32x16 B-fragment layout, bf16.
// bp[((ct*NK16 + ks)*64 + lane)*8 + i] = B[k][c]
//   k = ks*16 + (lane>>5)*8 + i,  c = ct*32 + (lane&31)  (permuted col)
// ---------------------------------------------------------------------------
__global__ void prep_bp32(int layer, int NK16,
                          const float* __restrict__ W0, const float* __restrict__ Wk,
                          const float* __restrict__ U, unsigned short* __restrict__ bp) {
    int idx = blockIdx.x * 256 + threadIdx.x;
    int total = 64 * NK16 * 64;
    if (idx >= total) return;
    int lane = idx & 63;
    int rest = idx >> 6;
    int ks = rest % NK16;
    int ct = rest / NK16;
    int c = ct * 32 + (lane & 31);
    int j = ((c >> 6) << 4) + (c & 15);
    int gate = (c >> 4) & 3;
    int sc = gate * 512 + j;
    int kbase = ks * 16 + ((lane >> 5) << 3);
    unsigned short outv[8];
#pragma unroll
    for (int i = 0; i < 8; i++) {
        int k = kbase + i;
        float v = 0.0f;
        if (layer == 0) {
            if (k < 8) { if (k < 6) v = W0[(size_t)k * 2048 + sc]; }
            else if (k < 520) v = U[(size_t)(k - 8) * 2048 + sc];
        } else {
            if (k < 512) v = Wk[((size_t)(layer - 1) * 512 + k) * 2048 + sc];
            else         v = U[((size_t)layer * 512 + (k - 512)) * 2048 + sc];
        }
        outv[i] = f2bf(v);
    }
    *(uint4*)(bp + (size_t)idx * 8) = *(const uint4*)outv;
}

// ---------------------------------------------------------------------------
// Diff input: d[t][item][0..7] bf16 (6 real features, padded)
// ---------------------------------------------------------------------------
__global__ void diffk(const float* __restrict__ x, const float* __restrict__ bound,
                      unsigned short* __restrict__ dbuf) {
    int idx = blockIdx.x * 256 + threadIdx.x;
    if (idx >= 255 * 128) return;
    int item = idx & 127, t = idx >> 7;
    const float* xr = x + ((size_t)item * 256 + t) * 6;
    unsigned short row[8];
#pragma unroll
    for (int f = 0; f < 6; f++) row[f] = f2bf((xr[6 + f] - xr[f]) / bound[f]);
    row[6] = 0; row[7] = 0;
    *(uint4*)(dbuf + (size_t)idx * 8) = *(const uint4*)row;
}

// ---------------------------------------------------------------------------
// Persistent LSTM: block = (layer l, colgroup cg 0..31, m-group mg 0..1).
// ---------------------------------------------------------------------------
__global__ __launch_bounds__(256, 1) void lstm_persist(
    const unsigned short* __restrict__ dbuf,
    unsigned short* __restrict__ hbuf,
    const unsigned short* __restrict__ bp_all,
    const float* __restrict__ bias,
    int* __restrict__ flags)
{
    extern __shared__ char smem[];
    float* zsm = (float*)smem;
    unsigned short* wsm = (unsigned short*)(smem + LDS_ZBYTES);

    const int blk   = blockIdx.x;
    const int layer = blk >> 6;
    const int cg    = (blk >> 1) & 31;
    const int mg    = blk & 1;
    const int tid   = threadIdx.x;
    const int w     = tid >> 6;
    const int lane  = tid & 63;
    const int NK16  = (layer == 0) ? 48 : 64;
    const int NCH   = NK16 >> 4;            // chunks of 16 k-steps: 3 or 4

    // ---- stage this block's weight tile into LDS (once) ------------------
    {
        const unsigned short* src = bp_all
            + (layer == 0 ? 0ull : (BPE_L0 + (size_t)(layer - 1) * BPE_STR))
            + (size_t)(cg * 2) * NK16 * 64 * 8;
        int nv = 2 * NK16 * 64;             // uint4 count (6144 or 8192)
        for (int e = tid; e < nv; e += 256)
            ((uint4*)wsm)[e] = ((const uint4*)src)[e];
    }
    __syncthreads();

    // ---- per-wave constants ----------------------------------------------
    const int mt    = w >> 1;               // m-half 0..1
    const int ntl   = w & 1;                // n-tile 0..1
    const int khalf = lane >> 5;            // k sub-group
    const int arow  = mg * 64 + mt * 32 + (lane & 31);
    // cell-phase constants
    const int citem = tid & 63;
    const int gitem = mg * 64 + citem;
    const int jj0   = (tid >> 6) * 4;
    const int jglob = cg * 16 + jj0;
    const f32x4 bI = *(const f32x4*)(bias + layer * 2048 + cg * 64 + 0  + jj0);
    const f32x4 bF = *(const f32x4*)(bias + layer * 2048 + cg * 64 + 16 + jj0);
    const f32x4 bG = *(const f32x4*)(bias + layer * 2048 + cg * 64 + 32 + jj0);
    const f32x4 bO = *(const f32x4*)(bias + layer * 2048 + cg * 64 + 48 + jj0);

    f32x4 creg = (f32x4){0.f, 0.f, 0.f, 0.f};      // c-state lives in registers

    for (int t = 0; t < 255; t++) {
        // ---- wait for producers: RELAXED spin, single ACQUIRE at the end -
        if (tid == 0) {
            if (layer > 0) {
                int* f = &flags[(t * 4 + (layer - 1)) * 2 + mg];
                while (__hip_atomic_load(f, __ATOMIC_RELAXED, __HIP_MEMORY_SCOPE_AGENT) < 32)
                    __builtin_amdgcn_s_sleep(1);
            }
            if (t > 0) {
                int* f2 = &flags[((t - 1) * 4 + layer) * 2 + mg];
                while (__hip_atomic_load(f2, __ATOMIC_RELAXED, __HIP_MEMORY_SCOPE_AGENT) < 32)
                    __builtin_amdgcn_s_sleep(1);
            }
            if (layer > 0 || t > 0) {
                int* fa = (layer > 0) ? &flags[(t * 4 + (layer - 1)) * 2 + mg]
                                      : &flags[((t - 1) * 4 + layer) * 2 + mg];
                (void)__hip_atomic_load(fa, __ATOMIC_ACQUIRE, __HIP_MEMORY_SCOPE_AGENT);
            }
        }
        __syncthreads();

        // ---- A base pointers ---------------------------------------------
        const unsigned short* pO = hbuf + (size_t)t * HSS + (size_t)layer * HLS
                                   + (size_t)arow * 512 + khalf * 8;
        const unsigned short* pP = nullptr;
        const unsigned short* pD = nullptr;
        if (layer > 0)
            pP = hbuf + (size_t)(t + 1) * HSS + (size_t)(layer - 1) * HLS
                 + (size_t)arow * 512 + khalf * 8;
        else
            pD = dbuf + ((size_t)t * 128 + arow) * 8;

        auto ld_a = [&](int kc) -> uint4 {
            if (layer == 0) {
                if (kc == 0 && khalf == 0) return *(const uint4*)pD;
                return *(const uint4*)(pO + kc * 16 - 8);
            }
            return (kc < 32) ? *(const uint4*)(pP + kc * 16)
                             : *(const uint4*)(pO + (kc - 32) * 16);
        };

        f32x16 acc = {0.f,0.f,0.f,0.f,0.f,0.f,0.f,0.f,0.f,0.f,0.f,0.f,0.f,0.f,0.f,0.f};
        uint4 bufA[16], bufB[16];

        auto issue = [&](uint4 (&buf)[16], int c0) {
#pragma unroll
            for (int i = 0; i < 16; i++) buf[i] = ld_a(c0 * 16 + i);
        };
        auto consume = [&](uint4 (&buf)[16], int c0) {
#pragma unroll
            for (int i = 0; i < 16; i++) {
                const bf16x8 bv = *(const bf16x8*)(wsm +
                    ((size_t)(ntl * NK16 + c0 * 16 + i) * 64 + lane) * 8);
                acc = __builtin_amdgcn_mfma_f32_32x32x16_bf16(
                    __builtin_bit_cast(bf16x8, buf[i]), bv, acc, 0, 0, 0);
            }
        };

        // ---- pipelined k-loop: 16-step chunks, ping-pong prefetch --------
        issue(bufA, 0);
        for (int c = 0; c < NCH; c += 2) {
            if (c + 1 < NCH) issue(bufB, c + 1);
            consume(bufA, c);
            if (c + 1 < NCH) {
                if (c + 2 < NCH) issue(bufA, c + 2);
                consume(bufB, c + 1);
            }
        }

        // ---- z -> LDS exchange (MFMA C layout -> [row][col]) -------------
        {
            const int col   = ntl * 32 + (lane & 31);
            const int rbase = mt * 32 + 4 * khalf;
#pragma unroll
            for (int r = 0; r < 16; r++) {
                int row = rbase + (r & 3) + 8 * (r >> 2);
                zsm[row * LDS_ZPAD + col] = acc[r];
            }
        }
        __syncthreads();

        // ---- cell update: thread -> (item, 4 consecutive j), c in regs ---
        {
            const float* zr = zsm + citem * LDS_ZPAD;
            f32x4 zi = *(const f32x4*)(zr + 0  + jj0);
            f32x4 zf = *(const f32x4*)(zr + 16 + jj0);
            f32x4 zg = *(const f32x4*)(zr + 32 + jj0);
            f32x4 zo = *(const f32x4*)(zr + 48 + jj0);
            unsigned short hq[4];
#pragma unroll
            for (int q = 0; q < 4; q++) {
                float i_ = fsig(zi[q] + bI[q]);
                float f_ = fsig(zf[q] + bF[q]);
                float g_ = ftanh(zg[q] + bG[q]);
                float o_ = fsig(zo[q] + bO[q]);
                float cn = f_ * creg[q] + i_ * g_;
                creg[q] = cn;
                hq[q] = f2bf(o_ * ftanh(cn));
            }
            // write-through store (sc0/sc1): reaches L3 before the release
            unsigned long long hpack;
            __builtin_memcpy(&hpack, hq, 8);
            unsigned long long* hp = (unsigned long long*)(hbuf
                + (size_t)(t + 1) * HSS + (size_t)layer * HLS
                + (size_t)gitem * 512 + jglob);
            __hip_atomic_store(hp, hpack, __ATOMIC_RELAXED, __HIP_MEMORY_SCOPE_AGENT);
        }
        __syncthreads();   // compiler emits vmcnt(0) before s_barrier: all waves' stores drained
        if (tid == 0)
            __hip_atomic_fetch_add(&flags[(t * 4 + layer) * 2 + mg], 1,
                                   __ATOMIC_RELEASE, __HIP_MEMORY_SCOPE_AGENT);
    }
}

// ---------------------------------------------------------------------------
// Head: out[b,s,d] = h3[223+s][b] . Wd[:,d] + bd[d];  pred = out*bound+centre
// ---------------------------------------------------------------------------
__global__ void headk(const unsigned short* __restrict__ hbuf,
                      const float* __restrict__ Wd, const float* __restrict__ bd,
                      const float* __restrict__ bound, const float* __restrict__ centre,
                      float* __restrict__ out) {
    int idx = blockIdx.x * 256 + threadIdx.x;
    if (idx >= 12288) return;
    int dd = idx % 3;
    int rest = idx / 3;
    int sdx = rest & 31;
    int b = rest >> 5;
    int t = 223 + sdx;
    const unsigned short* hr = hbuf + ((size_t)(t + 1) * 4 + 3) * HLS + (size_t)b * 512;
    float acc = 0.0f;
    for (int jj = 0; jj < 512; jj++) acc += bf2f(hr[jj]) * Wd[jj * 3 + dd];
    float o = acc + bd[dd];
    out[idx] = o;
    out[12288 + idx] = o * bound[dd] + centre[dd];
}

// ---------------------------------------------------------------------------
extern "C" void kernel_launch(void* const* d_in, const int* in_sizes, int n_in,
                              void* d_out, int out_size, void* d_ws, size_t ws_size,
                              hipStream_t stream) {
    const float* x      = (const float*)d_in[0];
    const float* centre = (const float*)d_in[1];
    const float* bound  = (const float*)d_in[2];
    const float* W0     = (const float*)d_in[3];
    const float* Wk     = (const float*)d_in[4];
    const float* U      = (const float*)d_in[5];
    const float* b      = (const float*)d_in[6];
    const float* Wd     = (const float*)d_in[7];
    const float* bd     = (const float*)d_in[8];

    char* ws = (char*)d_ws;
    unsigned short* hbuf    = (unsigned short*)(ws + OFF_H);
    unsigned short* dbuf    = (unsigned short*)(ws + OFF_D);
    float*          bias_ws = (float*)(ws + OFF_BIAS);
    int*            flags   = (int*)(ws + OFF_FLAG);
    unsigned short* bp      = (unsigned short*)(ws + OFF_BP);

    hipMemsetAsync(hbuf, 0, HSS * 2, stream);          // h slot 0 = h_{-1} = 0
    hipMemsetAsync(flags, 0, SZ_FLAG, stream);

    prep_bias<<<32, 256, 0, stream>>>(b, bias_ws);
    prep_bp32<<<768, 256, 0, stream>>>(0, 48, W0, Wk, U, bp);
    for (int l = 1; l < 4; l++)
        prep_bp32<<<1024, 256, 0, stream>>>(l, 64, W0, Wk, U,
                                            bp + BPE_L0 + (size_t)(l - 1) * BPE_STR);
    diffk<<<128, 256, 0, stream>>>(x, bound, dbuf);

    hipFuncSetAttribute((const void*)lstm_persist,
                        hipFuncAttributeMaxDynamicSharedMemorySize, LDS_TOTAL);
    lstm_persist<<<256, 256, LDS_TOTAL, stream>>>(dbuf, hbuf, bp, bias_ws, flags);

    headk<<<48, 256, 0, stream>>>(hbuf, Wd, bd, bound, centre, (float*)d_out);
}

// Round 5
// 2110.006 us; speedup vs baseline: 4.4081x; 4.1115x over previous
//
#include <hip/hip_runtime.h>
#include <cstdint>
#include <cstddef>

// ---------------------------------------------------------------------------
// LSTMModel: B=128, T=256(->255 diffs), F=6, H=512, L=4, S=32, D=3
// R5 (= R4 + asm fix): persistent kernel, weights LDS-resident.
//  - per-producer monotone flags (release STOREs, no RMW fan-in)
//  - h staged per-block contiguous (full-line sc0sc1 write-through)
//  - 64-lane single-shot dependency poll + one acquire load per step
// ---------------------------------------------------------------------------

typedef __bf16 bf16x8  __attribute__((ext_vector_type(8)));
typedef float  f32x4   __attribute__((ext_vector_type(4)));
typedef float  f32x16  __attribute__((ext_vector_type(16)));
typedef unsigned int u32x4 __attribute__((ext_vector_type(4)));

// stg geometry (elements)
#define STG_SLOT  262144ull     // 4l * 2mg * 32cg * 64item * 16j
#define STG_L     65536ull
#define STG_MG    32768ull
#define STG_CG    1024ull

// ws byte offsets
#define OFF_STG  0ull
#define SZ_STG   (256ull*STG_SLOT*2ull)             // 134217728
#define OFF_D    (OFF_STG + SZ_STG)
#define SZ_D     524288ull
#define OFF_BIAS (OFF_D + SZ_D)
#define SZ_BIAS  32768ull
#define OFF_FLAG (OFF_BIAS + SZ_BIAS)
#define SZ_FLAG  4096ull                            // int flags[4][2][32] used
#define OFF_BP   (OFF_FLAG + SZ_FLAG)
// bp element offsets (ushort elems)
#define BPE_L0   (64ull*48ull*64ull*8ull)           // 1572864 (l0, NK16=48)
#define BPE_STR  (64ull*64ull*64ull*8ull)           // 2097152 (l>=1, NK16=64)

#define LDS_ZPAD   72                                // zsm row stride (dwords)
#define LDS_ZBYTES 18432                             // 64*72*4
#define LDS_HBYTES 2048                              // h staging tile
#define LDS_WBYTES 131072                            // weights (max, l>=1)
#define LDS_TOTAL  (LDS_ZBYTES + LDS_HBYTES + LDS_WBYTES)   // 151552

__device__ __forceinline__ unsigned short f2bf(float f) {
    unsigned int u = __builtin_bit_cast(unsigned int, f);
    unsigned int lsb = (u >> 16) & 1u;
    u += 0x7fffu + lsb;
    return (unsigned short)(u >> 16);
}
__device__ __forceinline__ float bf2f(unsigned short s) {
    unsigned int u = ((unsigned int)s) << 16;
    return __builtin_bit_cast(float, u);
}
__device__ __forceinline__ float fsig(float x)  { return 1.0f / (1.0f + __expf(-x)); }
__device__ __forceinline__ float ftanh(float x) { float e = __expf(2.0f * x); return 1.0f - 2.0f / (e + 1.0f); }

// ---------------------------------------------------------------------------
__global__ void prep_bias(const float* __restrict__ b, float* __restrict__ bias_ws) {
    int idx = blockIdx.x * 256 + threadIdx.x;
    if (idx >= 4 * 2048) return;
    int l = idx >> 11, c = idx & 2047;
    int j = ((c >> 6) << 4) + (c & 15);
    int gate = (c >> 4) & 3;
    bias_ws[idx] = b[l * 2048 + gate * 512 + j];
}

// ---------------------------------------------------------------------------
// Weights in mfma_32x32x16 B-fragment layout, bf16 (see R2 notes).
// ---------------------------------------------------------------------------
__global__ void prep_bp32(int layer, int NK16,
                          const float* __restrict__ W0, const float* __restrict__ Wk,
                          const float* __restrict__ U, unsigned short* __restrict__ bp) {
    int idx = blockIdx.x * 256 + threadIdx.x;
    int total = 64 * NK16 * 64;
    if (idx >= total) return;
    int lane = idx & 63;
    int rest = idx >> 6;
    int ks = rest % NK16;
    int ct = rest / NK16;
    int c = ct * 32 + (lane & 31);
    int j = ((c >> 6) << 4) + (c & 15);
    int gate = (c >> 4) & 3;
    int sc = gate * 512 + j;
    int kbase = ks * 16 + ((lane >> 5) << 3);
    unsigned short outv[8];
#pragma unroll
    for (int i = 0; i < 8; i++) {
        int k = kbase + i;
        float v = 0.0f;
        if (layer == 0) {
            if (k < 8) { if (k < 6) v = W0[(size_t)k * 2048 + sc]; }
            else if (k < 520) v = U[(size_t)(k - 8) * 2048 + sc];
        } else {
            if (k < 512) v = Wk[((size_t)(layer - 1) * 512 + k) * 2048 + sc];
            else         v = U[((size_t)layer * 512 + (k - 512)) * 2048 + sc];
        }
        outv[i] = f2bf(v);
    }
    *(uint4*)(bp + (size_t)idx * 8) = *(const uint4*)outv;
}

// ---------------------------------------------------------------------------
__global__ void diffk(const float* __restrict__ x, const float* __restrict__ bound,
                      unsigned short* __restrict__ dbuf) {
    int idx = blockIdx.x * 256 + threadIdx.x;
    if (idx >= 255 * 128) return;
    int item = idx & 127, t = idx >> 7;
    const float* xr = x + ((size_t)item * 256 + t) * 6;
    unsigned short row[8];
#pragma unroll
    for (int f = 0; f < 6; f++) row[f] = f2bf((xr[6 + f] - xr[f]) / bound[f]);
    row[6] = 0; row[7] = 0;
    *(uint4*)(dbuf + (size_t)idx * 8) = *(const uint4*)row;
}

// ---------------------------------------------------------------------------
// Persistent LSTM: block = (layer l, colgroup cg 0..31, m-group mg 0..1).
// ---------------------------------------------------------------------------
__global__ __launch_bounds__(256, 1) void lstm_persist(
    const unsigned short* __restrict__ dbuf,
    unsigned short* __restrict__ stg,
    const unsigned short* __restrict__ bp_all,
    const float* __restrict__ bias,
    int* __restrict__ flags)
{
    extern __shared__ char smem[];
    float* zsm = (float*)smem;
    unsigned short* hs = (unsigned short*)(smem + LDS_ZBYTES);
    unsigned short* wsm = (unsigned short*)(smem + LDS_ZBYTES + LDS_HBYTES);

    const int blk   = blockIdx.x;
    const int layer = blk >> 6;
    const int cg    = (blk >> 1) & 31;
    const int mg    = blk & 1;
    const int tid   = threadIdx.x;
    const int w     = tid >> 6;
    const int lane  = tid & 63;
    const int NK16  = (layer == 0) ? 48 : 64;
    const int NCH   = NK16 >> 4;

    // ---- stage this block's weight tile into LDS (once) ------------------
    {
        const unsigned short* src = bp_all
            + (layer == 0 ? 0ull : (BPE_L0 + (size_t)(layer - 1) * BPE_STR))
            + (size_t)(cg * 2) * NK16 * 64 * 8;
        int nv = 2 * NK16 * 64;
        for (int e = tid; e < nv; e += 256)
            ((uint4*)wsm)[e] = ((const uint4*)src)[e];
    }
    __syncthreads();

    // ---- per-wave constants ----------------------------------------------
    const int mt    = w >> 1;
    const int ntl   = w & 1;
    const int khalf = lane >> 5;
    const int arow  = mg * 64 + mt * 32 + (lane & 31);
    const int aloc  = arow & 63;                 // item within mg-half
    // cell-phase constants
    const int citem = tid & 63;
    const int jj0   = (tid >> 6) * 4;
    const f32x4 bI = *(const f32x4*)(bias + layer * 2048 + cg * 64 + 0  + jj0);
    const f32x4 bF = *(const f32x4*)(bias + layer * 2048 + cg * 64 + 16 + jj0);
    const f32x4 bG = *(const f32x4*)(bias + layer * 2048 + cg * 64 + 32 + jj0);
    const f32x4 bO = *(const f32x4*)(bias + layer * 2048 + cg * 64 + 48 + jj0);

    // flag indices for the 64-lane poll
    int fidx, base_tgt;
    if (lane < 32) { fidx = (layer * 2 + mg) * 32 + lane; base_tgt = 0; }         // own layer, >= t
    else if (layer > 0) { fidx = ((layer - 1) * 2 + mg) * 32 + (lane - 32); base_tgt = 1; } // prev layer, >= t+1
    else { fidx = 0; base_tgt = -(1 << 30); }
    const int myflag = (layer * 2 + mg) * 32 + cg;

    f32x4 creg = (f32x4){0.f, 0.f, 0.f, 0.f};

    for (int t = 0; t < 255; t++) {
        // ---- wave0: poll both dependency sets in one 64-lane shot --------
        if (w == 0) {
            int tgt = base_tgt + t;
            if (lane < 32 && t == 0) tgt = -(1 << 30);
            for (;;) {
                int v = __hip_atomic_load(&flags[fidx], __ATOMIC_RELAXED,
                                          __HIP_MEMORY_SCOPE_AGENT);
                if (__all(v >= tgt)) break;
                __builtin_amdgcn_s_sleep(2);
            }
            if (lane == 0 && (t > 0 || layer > 0))
                (void)__hip_atomic_load(&flags[0], __ATOMIC_ACQUIRE,
                                        __HIP_MEMORY_SCOPE_AGENT);
        }
        __syncthreads();

        // ---- A bases in stg ----------------------------------------------
        // layer>=1: kc<32 -> h_{l-1} slot t+1 ; kc>=32 -> h_l slot t
        // layer 0 : kc==0,khalf==0 -> dbuf ; else hk=kc*16+khalf*8-8 in slot t
        const unsigned short* baseP = stg + (size_t)(t + 1) * STG_SLOT
            + (size_t)(layer - 1) * STG_L + (size_t)mg * STG_MG
            + (size_t)aloc * 16;
        const unsigned short* baseO = stg + (size_t)t * STG_SLOT
            + (size_t)layer * STG_L + (size_t)mg * STG_MG
            + (size_t)aloc * 16;
        const unsigned short* pD = dbuf + ((size_t)t * 128 + arow) * 8;

        auto ld_a = [&](int kc) -> uint4 {
            if (layer == 0) {
                if (kc == 0 && khalf == 0) return *(const uint4*)pD;
                int hk = kc * 16 + khalf * 8 - 8;
                return *(const uint4*)(baseO + (size_t)(hk >> 4) * STG_CG + (hk & 15));
            }
            if (kc < 32)
                return *(const uint4*)(baseP + (size_t)kc * STG_CG + khalf * 8);
            return *(const uint4*)(baseO + (size_t)(kc - 32) * STG_CG + khalf * 8);
        };

        f32x16 acc = {0.f,0.f,0.f,0.f,0.f,0.f,0.f,0.f,0.f,0.f,0.f,0.f,0.f,0.f,0.f,0.f};
        uint4 bufA[16], bufB[16];

        auto issue = [&](uint4 (&buf)[16], int c0) {
#pragma unroll
            for (int i = 0; i < 16; i++) buf[i] = ld_a(c0 * 16 + i);
        };
        auto consume = [&](uint4 (&buf)[16], int c0) {
#pragma unroll
            for (int i = 0; i < 16; i++) {
                const bf16x8 bv = *(const bf16x8*)(wsm +
                    ((size_t)(ntl * NK16 + c0 * 16 + i) * 64 + lane) * 8);
                acc = __builtin_amdgcn_mfma_f32_32x32x16_bf16(
                    __builtin_bit_cast(bf16x8, buf[i]), bv, acc, 0, 0, 0);
            }
        };

        issue(bufA, 0);
        for (int c = 0; c < NCH; c += 2) {
            if (c + 1 < NCH) issue(bufB, c + 1);
            consume(bufA, c);
            if (c + 1 < NCH) {
                if (c + 2 < NCH) issue(bufA, c + 2);
                consume(bufB, c + 1);
            }
        }

        // ---- z -> LDS exchange (MFMA C layout -> [row][col]) -------------
        {
            const int col   = ntl * 32 + (lane & 31);
            const int rbase = mt * 32 + 4 * khalf;
#pragma unroll
            for (int r = 0; r < 16; r++) {
                int row = rbase + (r & 3) + 8 * (r >> 2);
                zsm[row * LDS_ZPAD + col] = acc[r];
            }
        }
        __syncthreads();

        // ---- cell update -> h into LDS staging tile ----------------------
        {
            const float* zr = zsm + citem * LDS_ZPAD;
            f32x4 zi = *(const f32x4*)(zr + 0  + jj0);
            f32x4 zf = *(const f32x4*)(zr + 16 + jj0);
            f32x4 zg = *(const f32x4*)(zr + 32 + jj0);
            f32x4 zo = *(const f32x4*)(zr + 48 + jj0);
            unsigned short hq[4];
#pragma unroll
            for (int q = 0; q < 4; q++) {
                float i_ = fsig(zi[q] + bI[q]);
                float f_ = fsig(zf[q] + bF[q]);
                float g_ = ftanh(zg[q] + bG[q]);
                float o_ = fsig(zo[q] + bO[q]);
                float cn = f_ * creg[q] + i_ * g_;
                creg[q] = cn;
                hq[q] = f2bf(o_ * ftanh(cn));
            }
            unsigned long long hpack;
            __builtin_memcpy(&hpack, hq, 8);
            *(unsigned long long*)((char*)hs + citem * 32 + jj0 * 2) = hpack;
        }
        __syncthreads();

        // ---- wave0: coalesced full-line write-through + release flag -----
        if (w == 0) {
            const char* hsb = (const char*)hs;
            u32x4 v0 = *(const u32x4*)(hsb + lane * 16);
            u32x4 v1 = *(const u32x4*)(hsb + 1024 + lane * 16);
            char* g0 = (char*)(stg + (size_t)(t + 1) * STG_SLOT
                               + (size_t)layer * STG_L + (size_t)mg * STG_MG
                               + (size_t)cg * STG_CG) + lane * 16;
            char* g1 = g0 + 1024;
            asm volatile("global_store_dwordx4 %0, %1, off sc0 sc1"
                         :: "v"(g0), "v"(v0) : "memory");
            asm volatile("global_store_dwordx4 %0, %1, off sc0 sc1"
                         :: "v"(g1), "v"(v1) : "memory");
            if (lane == 0)
                __hip_atomic_store(&flags[myflag], t + 1, __ATOMIC_RELEASE,
                                   __HIP_MEMORY_SCOPE_AGENT);
        }
    }
}

// ---------------------------------------------------------------------------
// Head: out[b,s,d] = h3[223+s][b] . Wd[:,d] + bd[d];  pred = out*bound+centre
// ---------------------------------------------------------------------------
__global__ void headk(const unsigned short* __restrict__ stg,
                      const float* __restrict__ Wd, const float* __restrict__ bd,
                      const float* __restrict__ bound, const float* __restrict__ centre,
                      float* __restrict__ out) {
    int idx = blockIdx.x * 256 + threadIdx.x;
    if (idx >= 12288) return;
    int dd = idx % 3;
    int rest = idx / 3;
    int sdx = rest & 31;
    int b = rest >> 5;
    size_t base = (size_t)(224 + sdx) * STG_SLOT + 3ull * STG_L
                + (size_t)(b >> 6) * STG_MG + (size_t)(b & 63) * 16;
    float acc = 0.0f;
    for (int jj = 0; jj < 512; jj++) {
        unsigned short hv = stg[base + (size_t)(jj >> 4) * STG_CG + (jj & 15)];
        acc += bf2f(hv) * Wd[jj * 3 + dd];
    }
    float o = acc + bd[dd];
    out[idx] = o;
    out[12288 + idx] = o * bound[dd] + centre[dd];
}

// ---------------------------------------------------------------------------
extern "C" void kernel_launch(void* const* d_in, const int* in_sizes, int n_in,
                              void* d_out, int out_size, void* d_ws, size_t ws_size,
                              hipStream_t stream) {
    const float* x      = (const float*)d_in[0];
    const float* centre = (const float*)d_in[1];
    const float* bound  = (const float*)d_in[2];
    const float* W0     = (const float*)d_in[3];
    const float* Wk     = (const float*)d_in[4];
    const float* U      = (const float*)d_in[5];
    const float* b      = (const float*)d_in[6];
    const float* Wd     = (const float*)d_in[7];
    const float* bd     = (const float*)d_in[8];

    char* ws = (char*)d_ws;
    unsigned short* stg     = (unsigned short*)(ws + OFF_STG);
    unsigned short* dbuf    = (unsigned short*)(ws + OFF_D);
    float*          bias_ws = (float*)(ws + OFF_BIAS);
    int*            flags   = (int*)(ws + OFF_FLAG);
    unsigned short* bp      = (unsigned short*)(ws + OFF_BP);

    (void)hipMemsetAsync(stg, 0, STG_SLOT * 2, stream);      // slot 0 = h_{-1} = 0
    (void)hipMemsetAsync(flags, 0, SZ_FLAG, stream);

    prep_bias<<<32, 256, 0, stream>>>(b, bias_ws);
    prep_bp32<<<768, 256, 0, stream>>>(0, 48, W0, Wk, U, bp);
    for (int l = 1; l < 4; l++)
        prep_bp32<<<1024, 256, 0, stream>>>(l, 64, W0, Wk, U,
                                            bp + BPE_L0 + (size_t)(l - 1) * BPE_STR);
    diffk<<<128, 256, 0, stream>>>(x, bound, dbuf);

    (void)hipFuncSetAttribute((const void*)lstm_persist,
                              hipFuncAttributeMaxDynamicSharedMemorySize, LDS_TOTAL);
    lstm_persist<<<256, 256, LDS_TOTAL, stream>>>(dbuf, stg, bp, bias_ws, flags);

    headk<<<48, 256, 0, stream>>>(stg, Wd, bd, bound, centre, (float*)d_out);
}